// Round 4
// baseline (462.373 us; speedup 1.0000x reference)
//
#include <hip/hip_runtime.h>
#include <hip/hip_bf16.h>

// MSACMixer: B=8, S=4096, D=1024
// out = ((softmax(x@wg^T) . {conv3,conv5,conv7}(val)) * sigmoid(gate)) @ w_down^T
// where [gate,val] = x @ w_up^T
//
// R3: fixed LDS swizzle (chunk ^= (row>>1)&3 — 2-way max for 64B rows) + XCD-chunked
//     block swizzle (each XCD owns one bn column -> W panel stays L2-resident).

#define MB 8
#define SS 4096
#define DD 1024
#define MM (MB * SS)   // 32768 rows
#define KD 1024
#define NT 16          // K tiles of 64

typedef __attribute__((ext_vector_type(8))) short short8;
typedef __attribute__((ext_vector_type(4))) float f32x4;

static __device__ __forceinline__ unsigned short f2bf(float f) {
    union { float f; unsigned u; } a; a.f = f;
    unsigned u = a.u;
    unsigned r = (u + 0x7FFFu + ((u >> 16) & 1u)) >> 16;   // RNE
    return (unsigned short)r;
}
static __device__ __forceinline__ float bf2f(unsigned short b) {
    union { unsigned u; float f; } a; a.u = ((unsigned)b) << 16;
    return a.f;
}

// ---------------------------------------------------------------- cvt f32->bf16 (weights)
__global__ void cvt_f32_bf16(const float4* __restrict__ src, ushort4* __restrict__ dst, int n4) {
    int i = blockIdx.x * blockDim.x + threadIdx.x;
    int stride = gridDim.x * blockDim.x;
    for (; i < n4; i += stride) {
        float4 v = src[i];
        ushort4 o;
        o.x = f2bf(v.x); o.y = f2bf(v.y); o.z = f2bf(v.z); o.w = f2bf(v.w);
        dst[i] = o;
    }
}

// ---------------------------------------------------------------- transpose conv weights
__global__ void prep_wt(const float* __restrict__ w3, const float* __restrict__ w5,
                        const float* __restrict__ w7, float* __restrict__ wt) {
    int d = blockIdx.x * 256 + threadIdx.x;
    if (d >= DD) return;
    #pragma unroll
    for (int j = 0; j < 3; j++) wt[j * DD + d] = w3[d * 3 + j];
    #pragma unroll
    for (int j = 0; j < 5; j++) wt[(3 + j) * DD + d] = w5[d * 5 + j];
    #pragma unroll
    for (int j = 0; j < 7; j++) wt[(8 + j) * DD + d] = w7[d * 7 + j];
}

// ---------------------------------------------------------------- softmax gate weights + x cvt
__global__ void scale_cvt(const float* __restrict__ x, const float* __restrict__ wg,
                          unsigned short* __restrict__ xb, float* __restrict__ sw, int M) {
    int gw = (int)((blockIdx.x * (size_t)blockDim.x + threadIdx.x) >> 6);
    int lane = threadIdx.x & 63;
    if (gw >= M) return;
    const float* xr = x + (size_t)gw * DD + lane * 16;
    float4 xv[4];
    #pragma unroll
    for (int q = 0; q < 4; q++) xv[q] = ((const float4*)xr)[q];

    float s0 = 0.f, s1 = 0.f, s2 = 0.f;
    #pragma unroll
    for (int q = 0; q < 4; q++) {
        float4 w0 = ((const float4*)(wg + lane * 16))[q];
        float4 w1 = ((const float4*)(wg + DD + lane * 16))[q];
        float4 w2 = ((const float4*)(wg + 2 * DD + lane * 16))[q];
        s0 += xv[q].x*w0.x + xv[q].y*w0.y + xv[q].z*w0.z + xv[q].w*w0.w;
        s1 += xv[q].x*w1.x + xv[q].y*w1.y + xv[q].z*w1.z + xv[q].w*w1.w;
        s2 += xv[q].x*w2.x + xv[q].y*w2.y + xv[q].z*w2.z + xv[q].w*w2.w;
    }

    short8 ob[2];
    #pragma unroll
    for (int q = 0; q < 4; q++) {
        ob[q >> 1][(q & 1) * 4 + 0] = (short)f2bf(xv[q].x);
        ob[q >> 1][(q & 1) * 4 + 1] = (short)f2bf(xv[q].y);
        ob[q >> 1][(q & 1) * 4 + 2] = (short)f2bf(xv[q].z);
        ob[q >> 1][(q & 1) * 4 + 3] = (short)f2bf(xv[q].w);
    }
    *(short8*)(xb + (size_t)gw * DD + lane * 16) = ob[0];
    *(short8*)(xb + (size_t)gw * DD + lane * 16 + 8) = ob[1];

    #pragma unroll
    for (int off = 32; off >= 1; off >>= 1) {
        s0 += __shfl_xor(s0, off);
        s1 += __shfl_xor(s1, off);
        s2 += __shfl_xor(s2, off);
    }
    if (lane == 0) {
        float mx = fmaxf(s0, fmaxf(s1, s2));
        float e0 = expf(s0 - mx), e1 = expf(s1 - mx), e2 = expf(s2 - mx);
        float inv = 1.f / (e0 + e1 + e2);
        sw[(size_t)gw * 3 + 0] = e0 * inv;
        sw[(size_t)gw * 3 + 1] = e1 * inv;
        sw[(size_t)gw * 3 + 2] = e2 * inv;
    }
}

// ---------------------------------------------------------------- 256^2 8-phase MFMA GEMM
// Same ledger as R2 (see comments there). Swizzle: stored chunk = logical ^ ((row>>1)&3),
// applied on the pre-swizzled global source (write side) and the ds_read offset (read side).
template <int EPI>
__global__ __launch_bounds__(512, 2) void gemm8(
    const unsigned short* __restrict__ A,   // [M,1024]
    const unsigned short* __restrict__ W,   // [N,1024]
    unsigned short* __restrict__ og,
    unsigned short* __restrict__ ov,
    float* __restrict__ of)
{
    __shared__ __align__(16) char lds[131072];
    const int tid = threadIdx.x;
    const int wid = tid >> 6, lane = tid & 63;
    const int l15 = lane & 15, l4 = lane >> 4;
    const int wr = wid >> 2, wc = wid & 3;

    // XCD-chunked block swizzle: flat ids are round-robined over 8 XCDs; remap so each
    // XCD gets a contiguous chunk (= one bn column for gemm0). nwg % 8 == 0 here.
    const int nwgx = gridDim.x, nwg = nwgx * gridDim.y;
    const int flat = blockIdx.x + nwgx * blockIdx.y;
    const int swzb = (flat & 7) * (nwg >> 3) + (flat >> 3);
    const int bm = swzb % nwgx, bn = swzb / nwgx;

    const unsigned short* Ablk = A + (size_t)bm * 256 * KD;
    const unsigned short* Wblk = W + (size_t)bn * 256 * KD;

    // staging: dest chunk = linear (wave base + lane*16), source chunk pre-swizzled
    const int r0 = tid >> 2;                                    // relative row (both halves: f same)
    const int cch8 = ((((tid & 3) ^ ((r0 >> 1) & 3))) << 3);    // swizzled col elem
    const int dst0 = wid * 64 * 16;

    // read offsets: row base is a multiple of 16 -> f(row) = (l15>>1)&3
    const int swz = ((l15 >> 1) & 3) << 4;
    int aoff[2][4], boff[4];
    #pragma unroll
    for (int mh = 0; mh < 2; mh++)
        #pragma unroll
        for (int m = 0; m < 4; m++)
            aoff[mh][m] = (wr * 128 + mh * 64 + m * 16 + l15) * 64 + ((l4 * 16) ^ swz);
    #pragma unroll
    for (int n = 0; n < 4; n++)
        boff[n] = (wc * 64 + n * 16 + l15) * 64 + ((l4 * 16) ^ swz);

    f32x4 acc[8][4];
    #pragma unroll
    for (int m = 0; m < 8; m++)
        #pragma unroll
        for (int n = 0; n < 4; n++) acc[m][n] = (f32x4)0.f;

#define LDSA(b,h) (lds + (b) * 32768 + (h) * 16384)
#define LDSB(b,h) (lds + 65536 + (b) * 32768 + (h) * 16384)

#define STAGE(gp, lb, ke) do { \
    __builtin_amdgcn_global_load_lds( \
        (const __attribute__((address_space(1))) void*)((gp) + (size_t)r0 * KD + (ke) + cch8), \
        (__attribute__((address_space(3))) void*)((lb) + dst0), 16, 0, 0); \
    __builtin_amdgcn_global_load_lds( \
        (const __attribute__((address_space(1))) void*)((gp) + (size_t)(r0 + 128) * KD + (ke) + cch8), \
        (__attribute__((address_space(3))) void*)((lb) + 8192 + dst0), 16, 0, 0); \
  } while (0)

    // prologue
    STAGE(Ablk, LDSA(0,0), 0);
    STAGE(Wblk, LDSB(0,0), 0);
    STAGE(Ablk, LDSA(0,1), 32);
    STAGE(Wblk, LDSB(0,1), 32);
    STAGE(Ablk, LDSA(1,0), 64);
    STAGE(Wblk, LDSB(1,0), 64);
    asm volatile("s_waitcnt vmcnt(8)" ::: "memory");
    __builtin_amdgcn_s_barrier();

    short8 bf0, bf1, bf2, bf3;

#define MFMA16(mh) do { \
    __builtin_amdgcn_s_setprio(1); \
    acc[(mh)*4+0][0] = __builtin_amdgcn_mfma_f32_16x16x32_bf16(af0, bf0, acc[(mh)*4+0][0], 0, 0, 0); \
    acc[(mh)*4+0][1] = __builtin_amdgcn_mfma_f32_16x16x32_bf16(af0, bf1, acc[(mh)*4+0][1], 0, 0, 0); \
    acc[(mh)*4+0][2] = __builtin_amdgcn_mfma_f32_16x16x32_bf16(af0, bf2, acc[(mh)*4+0][2], 0, 0, 0); \
    acc[(mh)*4+0][3] = __builtin_amdgcn_mfma_f32_16x16x32_bf16(af0, bf3, acc[(mh)*4+0][3], 0, 0, 0); \
    acc[(mh)*4+1][0] = __builtin_amdgcn_mfma_f32_16x16x32_bf16(af1, bf0, acc[(mh)*4+1][0], 0, 0, 0); \
    acc[(mh)*4+1][1] = __builtin_amdgcn_mfma_f32_16x16x32_bf16(af1, bf1, acc[(mh)*4+1][1], 0, 0, 0); \
    acc[(mh)*4+1][2] = __builtin_amdgcn_mfma_f32_16x16x32_bf16(af1, bf2, acc[(mh)*4+1][2], 0, 0, 0); \
    acc[(mh)*4+1][3] = __builtin_amdgcn_mfma_f32_16x16x32_bf16(af1, bf3, acc[(mh)*4+1][3], 0, 0, 0); \
    acc[(mh)*4+2][0] = __builtin_amdgcn_mfma_f32_16x16x32_bf16(af2, bf0, acc[(mh)*4+2][0], 0, 0, 0); \
    acc[(mh)*4+2][1] = __builtin_amdgcn_mfma_f32_16x16x32_bf16(af2, bf1, acc[(mh)*4+2][1], 0, 0, 0); \
    acc[(mh)*4+2][2] = __builtin_amdgcn_mfma_f32_16x16x32_bf16(af2, bf2, acc[(mh)*4+2][2], 0, 0, 0); \
    acc[(mh)*4+2][3] = __builtin_amdgcn_mfma_f32_16x16x32_bf16(af2, bf3, acc[(mh)*4+2][3], 0, 0, 0); \
    acc[(mh)*4+3][0] = __builtin_amdgcn_mfma_f32_16x16x32_bf16(af3, bf0, acc[(mh)*4+3][0], 0, 0, 0); \
    acc[(mh)*4+3][1] = __builtin_amdgcn_mfma_f32_16x16x32_bf16(af3, bf1, acc[(mh)*4+3][1], 0, 0, 0); \
    acc[(mh)*4+3][2] = __builtin_amdgcn_mfma_f32_16x16x32_bf16(af3, bf2, acc[(mh)*4+3][2], 0, 0, 0); \
    acc[(mh)*4+3][3] = __builtin_amdgcn_mfma_f32_16x16x32_bf16(af3, bf3, acc[(mh)*4+3][3], 0, 0, 0); \
    __builtin_amdgcn_s_setprio(0); \
  } while (0)

#define PHASE(rb, kk, mh, LB, sgp, slb, ske, DV) do { \
    const char* ab = LDSA(rb, kk); \
    short8 af0 = *(const short8*)(ab + aoff[mh][0]); \
    short8 af1 = *(const short8*)(ab + aoff[mh][1]); \
    short8 af2 = *(const short8*)(ab + aoff[mh][2]); \
    short8 af3 = *(const short8*)(ab + aoff[mh][3]); \
    if (LB) { const char* bb = LDSB(rb, kk); \
        bf0 = *(const short8*)(bb + boff[0]); \
        bf1 = *(const short8*)(bb + boff[1]); \
        bf2 = *(const short8*)(bb + boff[2]); \
        bf3 = *(const short8*)(bb + boff[3]); } \
    STAGE(sgp, slb, ske); \
    __builtin_amdgcn_s_barrier(); \
    MFMA16(mh); \
    if (DV) asm volatile("s_waitcnt vmcnt(8)" ::: "memory"); \
    __builtin_amdgcn_s_barrier(); \
  } while (0)

    for (int it = 0; it < NT / 2; ++it) {
        const int t = 2 * it;
        const int k1h = (t + 1) * 64 + 32;
        const int k2  = (t + 2 < NT ? t + 2 : NT - 1) * 64;
        const int k3  = (t + 3 < NT ? t + 3 : NT - 1) * 64;
        PHASE(0, 0, 0, 1, Ablk, LDSA(1,1), k1h,     0);
        PHASE(0, 0, 1, 0, Wblk, LDSB(1,1), k1h,     1);
        PHASE(0, 1, 0, 1, Ablk, LDSA(0,0), k2,      0);
        PHASE(0, 1, 1, 0, Wblk, LDSB(0,0), k2,      1);
        PHASE(1, 0, 0, 1, Ablk, LDSA(0,1), k2 + 32, 0);
        PHASE(1, 0, 1, 0, Wblk, LDSB(0,1), k2 + 32, 1);
        PHASE(1, 1, 0, 1, Ablk, LDSA(1,0), k3,      0);
        PHASE(1, 1, 1, 0, Wblk, LDSB(1,0), k3,      1);
    }
    asm volatile("s_waitcnt vmcnt(0)" ::: "memory");

    const int grow0 = bm * 256 + wr * 128;
    const int gcol0 = bn * 256 + wc * 64;
    if (EPI == 0) {
        #pragma unroll
        for (int m = 0; m < 8; m++) {
            #pragma unroll
            for (int n = 0; n < 4; n++) {
                int gcol = gcol0 + n * 16 + l15;
                bool isgate = gcol < 1024;
                unsigned short* dst = isgate ? og : ov;
                int cc = isgate ? gcol : gcol - 1024;
                #pragma unroll
                for (int r = 0; r < 4; r++) {
                    int grow = grow0 + m * 16 + l4 * 4 + r;
                    float v = acc[m][n][r];
                    float o = isgate ? (1.f / (1.f + __expf(-v))) : v;
                    dst[(size_t)grow * 1024 + cc] = f2bf(o);
                }
            }
        }
    } else {
        #pragma unroll
        for (int m = 0; m < 8; m++) {
            #pragma unroll
            for (int n = 0; n < 4; n++) {
                int gcol = gcol0 + n * 16 + l15;
                #pragma unroll
                for (int r = 0; r < 4; r++) {
                    int grow = grow0 + m * 16 + l4 * 4 + r;
                    of[(size_t)grow * 1024 + gcol] = acc[m][n][r];
                }
            }
        }
    }
#undef PHASE
#undef MFMA16
#undef STAGE
#undef LDSA
#undef LDSB
}

// ---------------------------------------------------------------- conv + softmax-mix + gate
__global__ __launch_bounds__(256) void conv_mix(
    const unsigned short* __restrict__ val,
    unsigned short* __restrict__ ga,      // gate in / A2 out (in place)
    const float* __restrict__ sw,
    const float* __restrict__ wt)         // transposed taps [15][DD]
{
    const int tid = threadIdx.x;
    const int dg = tid & 63, sr = tid >> 6;
    const int half = blockIdx.x & 1;
    const size_t mgrp = (size_t)(blockIdx.x >> 1);
    const size_t m = mgrp * 4 + sr;
    const int s = (int)(m & (SS - 1));
    const int d0 = half * 512 + dg * 8;

    const float* w3t = wt;
    const float* w5t = wt + 3 * DD;
    const float* w7t = wt + 8 * DD;

    float c3[8], c5[8], c7[8];
    #pragma unroll
    for (int i = 0; i < 8; i++) { c3[i] = 0.f; c5[i] = 0.f; c7[i] = 0.f; }

    #pragma unroll
    for (int j = 0; j < 7; j++) {
        int soff = s - 6 + j;
        float v[8];
        if (soff >= 0) {
            short8 r = *(const short8*)(val + (m - 6 + j) * (size_t)DD + d0);
            #pragma unroll
            for (int i = 0; i < 8; i++) v[i] = bf2f((unsigned short)r[i]);
        } else {
            #pragma unroll
            for (int i = 0; i < 8; i++) v[i] = 0.f;
        }
        {
            const float4* p = (const float4*)(w7t + (size_t)j * DD + d0);
            float4 wa = p[0], wb = p[1];
            c7[0] += v[0]*wa.x; c7[1] += v[1]*wa.y; c7[2] += v[2]*wa.z; c7[3] += v[3]*wa.w;
            c7[4] += v[4]*wb.x; c7[5] += v[5]*wb.y; c7[6] += v[6]*wb.z; c7[7] += v[7]*wb.w;
        }
        if (j >= 2) {
            const float4* p = (const float4*)(w5t + (size_t)(j - 2) * DD + d0);
            float4 wa = p[0], wb = p[1];
            c5[0] += v[0]*wa.x; c5[1] += v[1]*wa.y; c5[2] += v[2]*wa.z; c5[3] += v[3]*wa.w;
            c5[4] += v[4]*wb.x; c5[5] += v[5]*wb.y; c5[6] += v[6]*wb.z; c5[7] += v[7]*wb.w;
        }
        if (j >= 4) {
            const float4* p = (const float4*)(w3t + (size_t)(j - 4) * DD + d0);
            float4 wa = p[0], wb = p[1];
            c3[0] += v[0]*wa.x; c3[1] += v[1]*wa.y; c3[2] += v[2]*wa.z; c3[3] += v[3]*wa.w;
            c3[4] += v[4]*wb.x; c3[5] += v[5]*wb.y; c3[6] += v[6]*wb.z; c3[7] += v[7]*wb.w;
        }
    }

    float s0 = sw[m * 3 + 0], s1 = sw[m * 3 + 1], s2 = sw[m * 3 + 2];
    short8 g = *(const short8*)(ga + m * (size_t)DD + d0);
    short8 o;
    #pragma unroll
    for (int i = 0; i < 8; i++) {
        float fused = s0 * c3[i] + s1 * c5[i] + s2 * c7[i];
        o[i] = (short)f2bf(fused * bf2f((unsigned short)g[i]));
    }
    *(short8*)(ga + m * (size_t)DD + d0) = o;
}

// ---------------------------------------------------------------- launch
extern "C" void kernel_launch(void* const* d_in, const int* in_sizes, int n_in,
                              void* d_out, int out_size, void* d_ws, size_t ws_size,
                              hipStream_t stream) {
    const float* x      = (const float*)d_in[0];
    const float* w_up   = (const float*)d_in[1];
    const float* w_down = (const float*)d_in[2];
    const float* w_gate = (const float*)d_in[3];
    const float* w3     = (const float*)d_in[4];
    const float* w5     = (const float*)d_in[5];
    const float* w7     = (const float*)d_in[6];
    float* out = (float*)d_out;

    char* ws = (char*)d_ws;
    const size_t NX = (size_t)MM * DD;
    unsigned short* xb   = (unsigned short*)ws;                               // 64 MiB
    unsigned short* wub  = (unsigned short*)(ws + NX * 2);                    // 4 MiB
    unsigned short* wdb  = (unsigned short*)(ws + NX * 2 + 4194304);          // 2 MiB
    unsigned short* gate = (unsigned short*)(ws + NX * 2 + 6291456);          // 64 MiB (becomes A2)
    unsigned short* valb = (unsigned short*)(ws + NX * 2 + 6291456 + NX * 2); // 64 MiB
    float*          sw   = (float*)(ws + NX * 2 + 6291456 + NX * 4);          // 384 KiB
    float*          wt   = (float*)(ws + NX * 2 + 6291456 + NX * 4 + 393216); // 60 KiB

    cvt_f32_bf16<<<512, 256, 0, stream>>>((const float4*)w_up, (ushort4*)wub, 2048 * 1024 / 4);
    cvt_f32_bf16<<<256, 256, 0, stream>>>((const float4*)w_down, (ushort4*)wdb, 1024 * 1024 / 4);
    prep_wt<<<4, 256, 0, stream>>>(w3, w5, w7, wt);
    scale_cvt<<<MM / 4, 256, 0, stream>>>(x, w_gate, xb, sw, MM);
    gemm8<0><<<dim3(MM / 256, 2048 / 256), 512, 0, stream>>>(xb, wub, gate, valb, nullptr);
    conv_mix<<<MM / 4 * 2, 256, 0, stream>>>(valb, gate, sw, wt);
    gemm8<1><<<dim3(MM / 256, 1024 / 256), 512, 0, stream>>>(gate, wdb, nullptr, nullptr, out);
    (void)in_sizes; (void)n_in; (void)out_size; (void)ws_size;
}

// Round 5
// 429.740 us; speedup vs baseline: 1.0759x; 1.0759x over previous
//
#include <hip/hip_runtime.h>
#include <hip/hip_bf16.h>

// MSACMixer: B=8, S=4096, D=1024
// out = ((softmax(x@wg^T) . {conv3,conv5,conv7}(val)) * sigmoid(gate)) @ w_down^T
// where [gate,val] = x @ w_up^T
//
// R4: XCD chunking on bm (each XCD owns 16 A-panels, sweeps bn inner -> A L2-resident,
//     fetched from L3 once per panel), LDS swizzle kept (0 conflicts), prep kernels merged.

#define MB 8
#define SS 4096
#define DD 1024
#define MM (MB * SS)   // 32768 rows
#define KD 1024
#define NT 16          // K tiles of 64

typedef __attribute__((ext_vector_type(8))) short short8;
typedef __attribute__((ext_vector_type(4))) float f32x4;

static __device__ __forceinline__ unsigned short f2bf(float f) {
    union { float f; unsigned u; } a; a.f = f;
    unsigned u = a.u;
    unsigned r = (u + 0x7FFFu + ((u >> 16) & 1u)) >> 16;   // RNE
    return (unsigned short)r;
}
static __device__ __forceinline__ float bf2f(unsigned short b) {
    union { unsigned u; float f; } a; a.u = ((unsigned)b) << 16;
    return a.f;
}

// ---------------------------------------------------------------- merged weight prep
// [0,n1): w_up cvt (float4->ushort4), [n1,n1+n2): w_down cvt, [n1+n2, +1024): conv wt transpose
__global__ void prep_misc(const float* __restrict__ w_up, const float* __restrict__ w_down,
                          const float* __restrict__ w3, const float* __restrict__ w5,
                          const float* __restrict__ w7,
                          ushort4* __restrict__ wub, ushort4* __restrict__ wdb,
                          float* __restrict__ wt) {
    const int n1 = 2048 * 1024 / 4, n2 = 1024 * 1024 / 4;
    int i = blockIdx.x * 256 + threadIdx.x;
    if (i < n1) {
        float4 v = ((const float4*)w_up)[i];
        ushort4 o; o.x = f2bf(v.x); o.y = f2bf(v.y); o.z = f2bf(v.z); o.w = f2bf(v.w);
        wub[i] = o;
    } else if (i < n1 + n2) {
        int j = i - n1;
        float4 v = ((const float4*)w_down)[j];
        ushort4 o; o.x = f2bf(v.x); o.y = f2bf(v.y); o.z = f2bf(v.z); o.w = f2bf(v.w);
        wdb[j] = o;
    } else if (i < n1 + n2 + DD) {
        int d = i - n1 - n2;
        #pragma unroll
        for (int j = 0; j < 3; j++) wt[j * DD + d] = w3[d * 3 + j];
        #pragma unroll
        for (int j = 0; j < 5; j++) wt[(3 + j) * DD + d] = w5[d * 5 + j];
        #pragma unroll
        for (int j = 0; j < 7; j++) wt[(8 + j) * DD + d] = w7[d * 7 + j];
    }
}

// ---------------------------------------------------------------- softmax gate weights + x cvt
__global__ void scale_cvt(const float* __restrict__ x, const float* __restrict__ wg,
                          unsigned short* __restrict__ xb, float* __restrict__ sw, int M) {
    int gw = (int)((blockIdx.x * (size_t)blockDim.x + threadIdx.x) >> 6);
    int lane = threadIdx.x & 63;
    if (gw >= M) return;
    const float* xr = x + (size_t)gw * DD + lane * 16;
    float4 xv[4];
    #pragma unroll
    for (int q = 0; q < 4; q++) xv[q] = ((const float4*)xr)[q];

    float s0 = 0.f, s1 = 0.f, s2 = 0.f;
    #pragma unroll
    for (int q = 0; q < 4; q++) {
        float4 w0 = ((const float4*)(wg + lane * 16))[q];
        float4 w1 = ((const float4*)(wg + DD + lane * 16))[q];
        float4 w2 = ((const float4*)(wg + 2 * DD + lane * 16))[q];
        s0 += xv[q].x*w0.x + xv[q].y*w0.y + xv[q].z*w0.z + xv[q].w*w0.w;
        s1 += xv[q].x*w1.x + xv[q].y*w1.y + xv[q].z*w1.z + xv[q].w*w1.w;
        s2 += xv[q].x*w2.x + xv[q].y*w2.y + xv[q].z*w2.z + xv[q].w*w2.w;
    }

    short8 ob[2];
    #pragma unroll
    for (int q = 0; q < 4; q++) {
        ob[q >> 1][(q & 1) * 4 + 0] = (short)f2bf(xv[q].x);
        ob[q >> 1][(q & 1) * 4 + 1] = (short)f2bf(xv[q].y);
        ob[q >> 1][(q & 1) * 4 + 2] = (short)f2bf(xv[q].z);
        ob[q >> 1][(q & 1) * 4 + 3] = (short)f2bf(xv[q].w);
    }
    *(short8*)(xb + (size_t)gw * DD + lane * 16) = ob[0];
    *(short8*)(xb + (size_t)gw * DD + lane * 16 + 8) = ob[1];

    #pragma unroll
    for (int off = 32; off >= 1; off >>= 1) {
        s0 += __shfl_xor(s0, off);
        s1 += __shfl_xor(s1, off);
        s2 += __shfl_xor(s2, off);
    }
    if (lane == 0) {
        float mx = fmaxf(s0, fmaxf(s1, s2));
        float e0 = expf(s0 - mx), e1 = expf(s1 - mx), e2 = expf(s2 - mx);
        float inv = 1.f / (e0 + e1 + e2);
        sw[(size_t)gw * 3 + 0] = e0 * inv;
        sw[(size_t)gw * 3 + 1] = e1 * inv;
        sw[(size_t)gw * 3 + 2] = e2 * inv;
    }
}

// ---------------------------------------------------------------- 256^2 8-phase MFMA GEMM
// Ledger as R2. LDS swizzle: stored chunk = logical ^ ((row>>1)&3) (0 conflicts, R3-verified).
// XCD map: k=flat&7 (XCD), j=flat>>3; bn=j%NBN, bm=j/NBN + k*(128/8). Each XCD owns 16
// bm-panels and sweeps bn innermost -> A panel fetched from L3 once, then L2-served.
template <int EPI, int NBN>
__global__ __launch_bounds__(512, 2) void gemm8(
    const unsigned short* __restrict__ A,   // [M,1024]
    const unsigned short* __restrict__ W,   // [N,1024]
    unsigned short* __restrict__ og,
    unsigned short* __restrict__ ov,
    float* __restrict__ of)
{
    __shared__ __align__(16) char lds[131072];
    const int tid = threadIdx.x;
    const int wid = tid >> 6, lane = tid & 63;
    const int l15 = lane & 15, l4 = lane >> 4;
    const int wr = wid >> 2, wc = wid & 3;

    const int flat = blockIdx.x + gridDim.x * blockIdx.y;
    const int k8 = flat & 7, j = flat >> 3;
    const int bn = j % NBN;
    const int bm = j / NBN + k8 * 16;       // gridDim.x == 128 always here

    const unsigned short* Ablk = A + (size_t)bm * 256 * KD;
    const unsigned short* Wblk = W + (size_t)bn * 256 * KD;

    const int r0 = tid >> 2;
    const int cch8 = ((((tid & 3) ^ ((r0 >> 1) & 3))) << 3);
    const int dst0 = wid * 64 * 16;

    const int swz = ((l15 >> 1) & 3) << 4;
    int aoff[2][4], boff[4];
    #pragma unroll
    for (int mh = 0; mh < 2; mh++)
        #pragma unroll
        for (int m = 0; m < 4; m++)
            aoff[mh][m] = (wr * 128 + mh * 64 + m * 16 + l15) * 64 + ((l4 * 16) ^ swz);
    #pragma unroll
    for (int n = 0; n < 4; n++)
        boff[n] = (wc * 64 + n * 16 + l15) * 64 + ((l4 * 16) ^ swz);

    f32x4 acc[8][4];
    #pragma unroll
    for (int m = 0; m < 8; m++)
        #pragma unroll
        for (int n = 0; n < 4; n++) acc[m][n] = (f32x4)0.f;

#define LDSA(b,h) (lds + (b) * 32768 + (h) * 16384)
#define LDSB(b,h) (lds + 65536 + (b) * 32768 + (h) * 16384)

#define STAGE(gp, lb, ke) do { \
    __builtin_amdgcn_global_load_lds( \
        (const __attribute__((address_space(1))) void*)((gp) + (size_t)r0 * KD + (ke) + cch8), \
        (__attribute__((address_space(3))) void*)((lb) + dst0), 16, 0, 0); \
    __builtin_amdgcn_global_load_lds( \
        (const __attribute__((address_space(1))) void*)((gp) + (size_t)(r0 + 128) * KD + (ke) + cch8), \
        (__attribute__((address_space(3))) void*)((lb) + 8192 + dst0), 16, 0, 0); \
  } while (0)

    // prologue
    STAGE(Ablk, LDSA(0,0), 0);
    STAGE(Wblk, LDSB(0,0), 0);
    STAGE(Ablk, LDSA(0,1), 32);
    STAGE(Wblk, LDSB(0,1), 32);
    STAGE(Ablk, LDSA(1,0), 64);
    STAGE(Wblk, LDSB(1,0), 64);
    asm volatile("s_waitcnt vmcnt(8)" ::: "memory");
    __builtin_amdgcn_s_barrier();

    short8 bf0, bf1, bf2, bf3;

#define MFMA16(mh) do { \
    __builtin_amdgcn_s_setprio(1); \
    acc[(mh)*4+0][0] = __builtin_amdgcn_mfma_f32_16x16x32_bf16(af0, bf0, acc[(mh)*4+0][0], 0, 0, 0); \
    acc[(mh)*4+0][1] = __builtin_amdgcn_mfma_f32_16x16x32_bf16(af0, bf1, acc[(mh)*4+0][1], 0, 0, 0); \
    acc[(mh)*4+0][2] = __builtin_amdgcn_mfma_f32_16x16x32_bf16(af0, bf2, acc[(mh)*4+0][2], 0, 0, 0); \
    acc[(mh)*4+0][3] = __builtin_amdgcn_mfma_f32_16x16x32_bf16(af0, bf3, acc[(mh)*4+0][3], 0, 0, 0); \
    acc[(mh)*4+1][0] = __builtin_amdgcn_mfma_f32_16x16x32_bf16(af1, bf0, acc[(mh)*4+1][0], 0, 0, 0); \
    acc[(mh)*4+1][1] = __builtin_amdgcn_mfma_f32_16x16x32_bf16(af1, bf1, acc[(mh)*4+1][1], 0, 0, 0); \
    acc[(mh)*4+1][2] = __builtin_amdgcn_mfma_f32_16x16x32_bf16(af1, bf2, acc[(mh)*4+1][2], 0, 0, 0); \
    acc[(mh)*4+1][3] = __builtin_amdgcn_mfma_f32_16x16x32_bf16(af1, bf3, acc[(mh)*4+1][3], 0, 0, 0); \
    acc[(mh)*4+2][0] = __builtin_amdgcn_mfma_f32_16x16x32_bf16(af2, bf0, acc[(mh)*4+2][0], 0, 0, 0); \
    acc[(mh)*4+2][1] = __builtin_amdgcn_mfma_f32_16x16x32_bf16(af2, bf1, acc[(mh)*4+2][1], 0, 0, 0); \
    acc[(mh)*4+2][2] = __builtin_amdgcn_mfma_f32_16x16x32_bf16(af2, bf2, acc[(mh)*4+2][2], 0, 0, 0); \
    acc[(mh)*4+2][3] = __builtin_amdgcn_mfma_f32_16x16x32_bf16(af2, bf3, acc[(mh)*4+2][3], 0, 0, 0); \
    acc[(mh)*4+3][0] = __builtin_amdgcn_mfma_f32_16x16x32_bf16(af3, bf0, acc[(mh)*4+3][0], 0, 0, 0); \
    acc[(mh)*4+3][1] = __builtin_amdgcn_mfma_f32_16x16x32_bf16(af3, bf1, acc[(mh)*4+3][1], 0, 0, 0); \
    acc[(mh)*4+3][2] = __builtin_amdgcn_mfma_f32_16x16x32_bf16(af3, bf2, acc[(mh)*4+3][2], 0, 0, 0); \
    acc[(mh)*4+3][3] = __builtin_amdgcn_mfma_f32_16x16x32_bf16(af3, bf3, acc[(mh)*4+3][3], 0, 0, 0); \
    __builtin_amdgcn_s_setprio(0); \
  } while (0)

#define PHASE(rb, kk, mh, LB, sgp, slb, ske, DV) do { \
    const char* ab = LDSA(rb, kk); \
    short8 af0 = *(const short8*)(ab + aoff[mh][0]); \
    short8 af1 = *(const short8*)(ab + aoff[mh][1]); \
    short8 af2 = *(const short8*)(ab + aoff[mh][2]); \
    short8 af3 = *(const short8*)(ab + aoff[mh][3]); \
    if (LB) { const char* bb = LDSB(rb, kk); \
        bf0 = *(const short8*)(bb + boff[0]); \
        bf1 = *(const short8*)(bb + boff[1]); \
        bf2 = *(const short8*)(bb + boff[2]); \
        bf3 = *(const short8*)(bb + boff[3]); } \
    STAGE(sgp, slb, ske); \
    __builtin_amdgcn_s_barrier(); \
    MFMA16(mh); \
    if (DV) asm volatile("s_waitcnt vmcnt(8)" ::: "memory"); \
    __builtin_amdgcn_s_barrier(); \
  } while (0)

    for (int it = 0; it < NT / 2; ++it) {
        const int t = 2 * it;
        const int k1h = (t + 1) * 64 + 32;
        const int k2  = (t + 2 < NT ? t + 2 : NT - 1) * 64;
        const int k3  = (t + 3 < NT ? t + 3 : NT - 1) * 64;
        PHASE(0, 0, 0, 1, Ablk, LDSA(1,1), k1h,     0);
        PHASE(0, 0, 1, 0, Wblk, LDSB(1,1), k1h,     1);
        PHASE(0, 1, 0, 1, Ablk, LDSA(0,0), k2,      0);
        PHASE(0, 1, 1, 0, Wblk, LDSB(0,0), k2,      1);
        PHASE(1, 0, 0, 1, Ablk, LDSA(0,1), k2 + 32, 0);
        PHASE(1, 0, 1, 0, Wblk, LDSB(0,1), k2 + 32, 1);
        PHASE(1, 1, 0, 1, Ablk, LDSA(1,0), k3,      0);
        PHASE(1, 1, 1, 0, Wblk, LDSB(1,0), k3,      1);
    }
    asm volatile("s_waitcnt vmcnt(0)" ::: "memory");

    const int grow0 = bm * 256 + wr * 128;
    const int gcol0 = bn * 256 + wc * 64;
    if (EPI == 0) {
        #pragma unroll
        for (int m = 0; m < 8; m++) {
            #pragma unroll
            for (int n = 0; n < 4; n++) {
                int gcol = gcol0 + n * 16 + l15;
                bool isgate = gcol < 1024;
                unsigned short* dst = isgate ? og : ov;
                int cc = isgate ? gcol : gcol - 1024;
                #pragma unroll
                for (int r = 0; r < 4; r++) {
                    int grow = grow0 + m * 16 + l4 * 4 + r;
                    float v = acc[m][n][r];
                    float o = isgate ? (1.f / (1.f + __expf(-v))) : v;
                    dst[(size_t)grow * 1024 + cc] = f2bf(o);
                }
            }
        }
    } else {
        #pragma unroll
        for (int m = 0; m < 8; m++) {
            #pragma unroll
            for (int n = 0; n < 4; n++) {
                int gcol = gcol0 + n * 16 + l15;
                #pragma unroll
                for (int r = 0; r < 4; r++) {
                    int grow = grow0 + m * 16 + l4 * 4 + r;
                    of[(size_t)grow * 1024 + gcol] = acc[m][n][r];
                }
            }
        }
    }
#undef PHASE
#undef MFMA16
#undef STAGE
#undef LDSA
#undef LDSB
}

// ---------------------------------------------------------------- conv + softmax-mix + gate
__global__ __launch_bounds__(256) void conv_mix(
    const unsigned short* __restrict__ val,
    unsigned short* __restrict__ ga,      // gate in / A2 out (in place)
    const float* __restrict__ sw,
    const float* __restrict__ wt)         // transposed taps [15][DD]
{
    const int tid = threadIdx.x;
    const int dg = tid & 63, sr = tid >> 6;
    const int half = blockIdx.x & 1;
    const size_t mgrp = (size_t)(blockIdx.x >> 1);
    const size_t m = mgrp * 4 + sr;
    const int s = (int)(m & (SS - 1));
    const int d0 = half * 512 + dg * 8;

    const float* w3t = wt;
    const float* w5t = wt + 3 * DD;
    const float* w7t = wt + 8 * DD;

    float c3[8], c5[8], c7[8];
    #pragma unroll
    for (int i = 0; i < 8; i++) { c3[i] = 0.f; c5[i] = 0.f; c7[i] = 0.f; }

    #pragma unroll
    for (int j = 0; j < 7; j++) {
        int soff = s - 6 + j;
        float v[8];
        if (soff >= 0) {
            short8 r = *(const short8*)(val + (m - 6 + j) * (size_t)DD + d0);
            #pragma unroll
            for (int i = 0; i < 8; i++) v[i] = bf2f((unsigned short)r[i]);
        } else {
            #pragma unroll
            for (int i = 0; i < 8; i++) v[i] = 0.f;
        }
        {
            const float4* p = (const float4*)(w7t + (size_t)j * DD + d0);
            float4 wa = p[0], wb = p[1];
            c7[0] += v[0]*wa.x; c7[1] += v[1]*wa.y; c7[2] += v[2]*wa.z; c7[3] += v[3]*wa.w;
            c7[4] += v[4]*wb.x; c7[5] += v[5]*wb.y; c7[6] += v[6]*wb.z; c7[7] += v[7]*wb.w;
        }
        if (j >= 2) {
            const float4* p = (const float4*)(w5t + (size_t)(j - 2) * DD + d0);
            float4 wa = p[0], wb = p[1];
            c5[0] += v[0]*wa.x; c5[1] += v[1]*wa.y; c5[2] += v[2]*wa.z; c5[3] += v[3]*wa.w;
            c5[4] += v[4]*wb.x; c5[5] += v[5]*wb.y; c5[6] += v[6]*wb.z; c5[7] += v[7]*wb.w;
        }
        if (j >= 4) {
            const float4* p = (const float4*)(w3t + (size_t)(j - 4) * DD + d0);
            float4 wa = p[0], wb = p[1];
            c3[0] += v[0]*wa.x; c3[1] += v[1]*wa.y; c3[2] += v[2]*wa.z; c3[3] += v[3]*wa.w;
            c3[4] += v[4]*wb.x; c3[5] += v[5]*wb.y; c3[6] += v[6]*wb.z; c3[7] += v[7]*wb.w;
        }
    }

    float s0 = sw[m * 3 + 0], s1 = sw[m * 3 + 1], s2 = sw[m * 3 + 2];
    short8 g = *(const short8*)(ga + m * (size_t)DD + d0);
    short8 o;
    #pragma unroll
    for (int i = 0; i < 8; i++) {
        float fused = s0 * c3[i] + s1 * c5[i] + s2 * c7[i];
        o[i] = (short)f2bf(fused * bf2f((unsigned short)g[i]));
    }
    *(short8*)(ga + m * (size_t)DD + d0) = o;
}

// ---------------------------------------------------------------- launch
extern "C" void kernel_launch(void* const* d_in, const int* in_sizes, int n_in,
                              void* d_out, int out_size, void* d_ws, size_t ws_size,
                              hipStream_t stream) {
    const float* x      = (const float*)d_in[0];
    const float* w_up   = (const float*)d_in[1];
    const float* w_down = (const float*)d_in[2];
    const float* w_gate = (const float*)d_in[3];
    const float* w3     = (const float*)d_in[4];
    const float* w5     = (const float*)d_in[5];
    const float* w7     = (const float*)d_in[6];
    float* out = (float*)d_out;

    char* ws = (char*)d_ws;
    const size_t NX = (size_t)MM * DD;
    unsigned short* xb   = (unsigned short*)ws;                               // 64 MiB
    unsigned short* wub  = (unsigned short*)(ws + NX * 2);                    // 4 MiB
    unsigned short* wdb  = (unsigned short*)(ws + NX * 2 + 4194304);          // 2 MiB
    unsigned short* gate = (unsigned short*)(ws + NX * 2 + 6291456);          // 64 MiB (becomes A2)
    unsigned short* valb = (unsigned short*)(ws + NX * 2 + 6291456 + NX * 2); // 64 MiB
    float*          sw   = (float*)(ws + NX * 2 + 6291456 + NX * 4);          // 384 KiB
    float*          wt   = (float*)(ws + NX * 2 + 6291456 + NX * 4 + 393216); // 60 KiB

    prep_misc<<<(2048*1024/4 + 1024*1024/4 + DD + 255) / 256, 256, 0, stream>>>(
        w_up, w_down, w3, w5, w7, (ushort4*)wub, (ushort4*)wdb, wt);
    scale_cvt<<<MM / 4, 256, 0, stream>>>(x, w_gate, xb, sw, MM);
    gemm8<0, 8><<<dim3(MM / 256, 2048 / 256), 512, 0, stream>>>(xb, wub, gate, valb, nullptr);
    conv_mix<<<MM / 4 * 2, 256, 0, stream>>>(valb, gate, sw, wt);
    gemm8<1, 4><<<dim3(MM / 256, 1024 / 256), 512, 0, stream>>>(gate, wdb, nullptr, nullptr, out);
    (void)in_sizes; (void)n_in; (void)out_size; (void)ws_size;
}